// Round 2
// baseline (1643.961 us; speedup 1.0000x reference)
//
#include <hip/hip_runtime.h>
#include <stdint.h>

// ---------- helpers ----------
typedef __attribute__((ext_vector_type(8))) short short8;
typedef __attribute__((ext_vector_type(4))) short short4v;
typedef __attribute__((ext_vector_type(4))) float float4v;

__device__ inline float b2f(unsigned short u) {
  union { unsigned int i; float f; } v; v.i = ((unsigned int)u) << 16; return v.f;
}
__device__ inline unsigned short f2b(float f) {
  union { float f; unsigned int i; } v; v.f = f;
  unsigned int i = v.i;
  i += 0x7fffu + ((i >> 16) & 1u);   // round-to-nearest-even
  return (unsigned short)(i >> 16);
}

// ---------- transpose fp32 -> bf16, zero-padded output (pad pre-zeroed by memset) ----------
__global__ void transpose_pad(const float* __restrict__ in, short* __restrict__ out,
                              int R, int C, int outStride, int total) {
  int idx = blockIdx.x * blockDim.x + threadIdx.x;
  if (idx >= total) return;
  int r = idx / C, c = idx - r * C;
  out[(size_t)c * outStride + r] = (short)f2b(in[idx]);
}

// ---------- edge scatter: agg[dst] += node[src] + w0[ef0] + b0 + w1[ef1] + b1 ----------
__global__ void edge_scatter(const float* __restrict__ nf,
                             const int* __restrict__ src, const int* __restrict__ dst,
                             const int* __restrict__ ef0, const int* __restrict__ ef1,
                             const float* __restrict__ w0, const float* __restrict__ b0,
                             const float* __restrict__ w1, const float* __restrict__ b1,
                             float* __restrict__ agg, int D, int quads, int total) {
  int idx = blockIdx.x * blockDim.x + threadIdx.x;
  if (idx >= total) return;
  int e = idx / quads;
  int q = idx - e * quads;
  int d = q * 4;
  int s  = src[e], dn = dst[e], f0 = ef0[e], f1 = ef1[e];
  float4v nv  = *(const float4v*)&nf[(size_t)s * D + d];
  float4v w0v = *(const float4v*)&w0[(size_t)f0 * D + d];
  float4v w1v = *(const float4v*)&w1[(size_t)f1 * D + d];
  float4v b0v = *(const float4v*)&b0[d];
  float4v b1v = *(const float4v*)&b1[d];
  float* ap = &agg[(size_t)dn * D + d];
#pragma unroll
  for (int j = 0; j < 4; ++j) {
    float v = nv[j] + w0v[j] + b0v[j] + w1v[j] + b1v[j];
    unsafeAtomicAdd(ap + j, v);   // native global_atomic_add_f32
  }
}

// ---------- MFMA GEMM: C = act(A @ B + bias), B given transposed+padded bf16 ----------
// A: MxK (fp32 or bf16), BT: [n][k] bf16 with ldbt=KP (zero-padded rows/cols),
// C: fp32 or bf16 MxNn. Optional per-column sum/sumsq atomics for BatchNorm.
template<bool AF32, bool RELU, bool STATS, bool CF32>
__global__ __launch_bounds__(256)
void gemm_bias(const void* __restrict__ Av, int lda,
               const short* __restrict__ BT, int ldbt,
               const float* __restrict__ bias,
               void* __restrict__ Cv, int ldc,
               int M, int Nn, int K, int KP,
               float* __restrict__ colsum, float* __restrict__ colsumsq) {
  constexpr int BM = 128, BN = 64, BK = 32, SA = 40;  // SA: padded LDS stride (bf16)
  __shared__ __align__(16) short Al[BM * SA];
  __shared__ __align__(16) short Bl[BN * SA];
  const int t = threadIdx.x;
  const int m0 = blockIdx.y * BM;
  const int n0 = blockIdx.x * BN;
  const int wave = t >> 6, lane = t & 63, quad = lane >> 4, lr = lane & 15;
  const int wm = (wave >> 1) * 64, wn = (wave & 1) * 32;

  const float4v fzero = {0.f, 0.f, 0.f, 0.f};
  float4v acc[4][2];
#pragma unroll
  for (int mi = 0; mi < 4; ++mi)
#pragma unroll
    for (int ni = 0; ni < 2; ++ni) acc[mi][ni] = fzero;

  const short4v z4 = {0, 0, 0, 0};
  const short8  z8 = {0, 0, 0, 0, 0, 0, 0, 0};

  for (int k0 = 0; k0 < KP; k0 += BK) {
    __syncthreads();
    // ---- stage A tile (BM x BK) into LDS as bf16, zero-fill OOB ----
    if constexpr (AF32) {
      const float* A = (const float*)Av;
#pragma unroll
      for (int l = 0; l < 4; ++l) {
        int g = t + l * 256;            // 0..1023
        int row = g >> 3, c = (g & 7) << 2;
        int gm = m0 + row, gk = k0 + c;
        short4v v = z4;
        if (gm < M && gk < K) {         // K%4==0 -> group fully valid or fully OOB
          float4v a = *(const float4v*)&A[(size_t)gm * lda + gk];
          v[0] = (short)f2b(a[0]); v[1] = (short)f2b(a[1]);
          v[2] = (short)f2b(a[2]); v[3] = (short)f2b(a[3]);
        }
        *(short4v*)&Al[row * SA + c] = v;
      }
    } else {
      const short* A = (const short*)Av;
#pragma unroll
      for (int l = 0; l < 2; ++l) {
        int g = t + l * 256;            // 0..511
        int row = g >> 2, c = (g & 3) << 3;
        int gm = m0 + row, gk = k0 + c;
        short8 v = z8;
        if (gm < M && gk < K)           // K%8==0
          v = *(const short8*)&A[(size_t)gm * lda + gk];
        *(short8*)&Al[row * SA + c] = v;
      }
    }
    // ---- stage BT tile (BN x BK); rows/cols pre-padded with zeros ----
    {
      int row = t >> 2, c = (t & 3) << 3;
      *(short8*)&Bl[row * SA + c] = *(const short8*)&BT[(size_t)(n0 + row) * ldbt + k0 + c];
    }
    __syncthreads();
    // ---- fragments + MFMA ----
    short8 af[4], bfr[2];
#pragma unroll
    for (int mi = 0; mi < 4; ++mi)
      af[mi] = *(short8*)&Al[(wm + mi * 16 + lr) * SA + quad * 8];
#pragma unroll
    for (int ni = 0; ni < 2; ++ni)
      bfr[ni] = *(short8*)&Bl[(wn + ni * 16 + lr) * SA + quad * 8];
#pragma unroll
    for (int mi = 0; mi < 4; ++mi)
#pragma unroll
      for (int ni = 0; ni < 2; ++ni)
        acc[mi][ni] = __builtin_amdgcn_mfma_f32_16x16x32_bf16(af[mi], bfr[ni], acc[mi][ni], 0, 0, 0);
  }

  // ---- epilogue: bias (+ReLU) (+column stats), store ----
#pragma unroll
  for (int ni = 0; ni < 2; ++ni) {
    int gn = n0 + wn + ni * 16 + lr;
    bool ncol = (gn < Nn);
    float bv = ncol ? bias[gn] : 0.f;
    float s = 0.f, q = 0.f;
#pragma unroll
    for (int mi = 0; mi < 4; ++mi) {
      int gmb = m0 + wm + mi * 16 + quad * 4;
#pragma unroll
      for (int r = 0; r < 4; ++r) {
        int gm = gmb + r;
        float v = acc[mi][ni][r] + bv;
        if (RELU) v = fmaxf(v, 0.f);
        if (gm < M && ncol) {
          if constexpr (CF32) ((float*)Cv)[(size_t)gm * ldc + gn] = v;
          else ((unsigned short*)Cv)[(size_t)gm * ldc + gn] = f2b(v);
          if (STATS) { s += v; q += v * v; }
        }
      }
    }
    if constexpr (STATS) {
      s += __shfl_xor(s, 16); q += __shfl_xor(q, 16);
      s += __shfl_xor(s, 32); q += __shfl_xor(q, 32);
      if (quad == 0 && ncol) {
        unsafeAtomicAdd(&colsum[gn], s);
        unsafeAtomicAdd(&colsumsq[gn], q);
      }
    }
  }
}

// ---------- BatchNorm finalize: scale/shift per column ----------
__global__ void bn_finalize(const float* __restrict__ colsum, const float* __restrict__ colsumsq,
                            const float* __restrict__ gamma, const float* __restrict__ beta,
                            float2* __restrict__ ss, int D, float invN) {
  int d = blockIdx.x * blockDim.x + threadIdx.x;
  if (d >= D) return;
  float mean = colsum[d] * invN;
  float var = fmaxf(colsumsq[d] * invN - mean * mean, 0.f);
  float sc = rsqrtf(var + 1e-5f) * gamma[d];
  float sh = beta[d] - mean * sc;
  ss[d] = make_float2(sc, sh);
}

// ---------- BatchNorm apply (in place on d_out, fp32) ----------
__global__ void bn_apply(float* __restrict__ out, const float2* __restrict__ ss,
                         int total, int D) {
  int idx = blockIdx.x * blockDim.x + threadIdx.x;
  if (idx >= total) return;
  int col = idx % D;
  float2 p = ss[col];
  out[idx] = out[idx] * p.x + p.y;
}

// ---------- launch ----------
extern "C" void kernel_launch(void* const* d_in, const int* in_sizes, int n_in,
                              void* d_out, int out_size, void* d_ws, size_t ws_size,
                              hipStream_t stream) {
  const float* nf  = (const float*)d_in[0];
  const int*   src = (const int*)d_in[1];
  const int*   dst = (const int*)d_in[2];
  const int*   ef0 = (const int*)d_in[3];
  const int*   ef1 = (const int*)d_in[4];
  const float* ew0 = (const float*)d_in[5];
  const float* eb0 = (const float*)d_in[6];
  const float* ew1 = (const float*)d_in[7];
  const float* eb1 = (const float*)d_in[8];
  const float* w1  = (const float*)d_in[9];
  const float* b1  = (const float*)d_in[10];
  const float* w2  = (const float*)d_in[11];
  const float* b2  = (const float*)d_in[12];
  const float* gam = (const float*)d_in[13];
  const float* bet = (const float*)d_in[14];

  const int D = in_sizes[13];        // 300
  const int N = in_sizes[0] / D;     // 100000
  const int E = in_sizes[1];         // 200000
  const int H = in_sizes[10];        // 600
  const int KP1 = (D + 31) / 32 * 32;  // 320
  const int NP1 = (H + 63) / 64 * 64;  // 640
  const int KP2 = (H + 31) / 32 * 32;  // 608
  const int NP2 = (D + 63) / 64 * 64;  // 320

  char* ws = (char*)d_ws;
  size_t off = 0;
  float* agg      = (float*)(ws + off); off += (size_t)N * D * 4;
  float* colsum   = (float*)(ws + off); off += 4096;
  float* colsumsq = (float*)(ws + off); off += 4096;
  short* wT1      = (short*)(ws + off); off += (size_t)NP1 * KP1 * 2;
  short* wT2      = (short*)(ws + off); off += (size_t)NP2 * KP2 * 2;
  size_t zero_bytes = off;
  float2* ss      = (float2*)(ws + off); off += 4096;
  short* h1       = (short*)(ws + off); off += (size_t)N * H * 2;

  hipMemsetAsync(d_ws, 0, zero_bytes, stream);

  {  // w1: (D x H) fp32 -> wT1: (H rows x KP1 cols) bf16
    int tot = D * H;
    transpose_pad<<<(tot + 255) / 256, 256, 0, stream>>>(w1, wT1, D, H, KP1, tot);
  }
  {  // w2: (H x D) fp32 -> wT2: (D rows x KP2 cols) bf16
    int tot = H * D;
    transpose_pad<<<(tot + 255) / 256, 256, 0, stream>>>(w2, wT2, H, D, KP2, tot);
  }
  {
    int quads = D / 4;
    int tot = E * quads;
    edge_scatter<<<(tot + 255) / 256, 256, 0, stream>>>(nf, src, dst, ef0, ef1,
                                                        ew0, eb0, ew1, eb1, agg, D, quads, tot);
  }
  {  // h1 = relu(agg @ w1 + b1), bf16 out
    dim3 grid(NP1 / 64, (N + 127) / 128);
    gemm_bias<true, true, false, false><<<grid, 256, 0, stream>>>(
        agg, D, wT1, KP1, b1, h1, H, N, H, D, KP1, nullptr, nullptr);
  }
  {  // h = h1 @ w2 + b2 (+ column stats), fp32 out
    dim3 grid(NP2 / 64, (N + 127) / 128);
    gemm_bias<false, false, true, true><<<grid, 256, 0, stream>>>(
        h1, H, wT2, KP2, b2, d_out, D, N, D, H, KP2, colsum, colsumsq);
  }
  bn_finalize<<<(D + 255) / 256, 256, 0, stream>>>(colsum, colsumsq, gam, bet, ss, D,
                                                   1.0f / (float)N);
  {
    int tot = N * D;
    bn_apply<<<(tot + 255) / 256, 256, 0, stream>>>((float*)d_out, ss, tot, D);
  }
}

// Round 3
// 687.020 us; speedup vs baseline: 2.3929x; 2.3929x over previous
//
#include <hip/hip_runtime.h>
#include <stdint.h>

// ---------- helpers ----------
typedef __attribute__((ext_vector_type(8))) short short8;
typedef __attribute__((ext_vector_type(4))) short short4v;
typedef __attribute__((ext_vector_type(4))) float float4v;

__device__ inline float b2f(unsigned short u) {
  union { unsigned int i; float f; } v; v.i = ((unsigned int)u) << 16; return v.f;
}
__device__ inline unsigned short f2b(float f) {
  union { float f; unsigned int i; } v; v.f = f;
  unsigned int i = v.i;
  i += 0x7fffu + ((i >> 16) & 1u);   // round-to-nearest-even
  return (unsigned short)(i >> 16);
}

// ---------- transpose fp32 -> bf16, zero-padded output (pad pre-zeroed by memset) ----------
__global__ void transpose_pad(const float* __restrict__ in, short* __restrict__ out,
                              int R, int C, int outStride, int total) {
  int idx = blockIdx.x * blockDim.x + threadIdx.x;
  if (idx >= total) return;
  int r = idx / C, c = idx - r * C;
  out[(size_t)c * outStride + r] = (short)f2b(in[idx]);
}

// ---------- CSR build: count, scan, fill ----------
__global__ void count_deg(const int* __restrict__ dst, int* __restrict__ deg, int E) {
  int e = blockIdx.x * blockDim.x + threadIdx.x;
  if (e < E) atomicAdd(&deg[dst[e]], 1);
}

// block of 256 threads scans 1024 elements; offp gets block-local exclusive scan,
// bsum[b] gets block total
__global__ void scan1(const int* __restrict__ deg, int* __restrict__ offp,
                      int* __restrict__ bsum, int n) {
  __shared__ int sh[256];
  const int t = threadIdx.x;
  const int base = blockIdx.x * 1024 + t * 4;
  int v[4], s = 0;
#pragma unroll
  for (int j = 0; j < 4; ++j) { int i = base + j; v[j] = (i < n) ? deg[i] : 0; s += v[j]; }
  sh[t] = s;
  __syncthreads();
  for (int d = 1; d < 256; d <<= 1) {
    int x = (t >= d) ? sh[t - d] : 0;
    __syncthreads();
    sh[t] += x;
    __syncthreads();
  }
  int excl = (t > 0) ? sh[t - 1] : 0;
  if (t == 255) bsum[blockIdx.x] = sh[255];
#pragma unroll
  for (int j = 0; j < 4; ++j) { int i = base + j; if (i < n) offp[i] = excl; excl += v[j]; }
}

// single block: exclusive-scan bsum in place (nb <= 256)
__global__ void scan2(int* __restrict__ bsum, int nb) {
  __shared__ int sh[256];
  const int t = threadIdx.x;
  sh[t] = (t < nb) ? bsum[t] : 0;
  __syncthreads();
  for (int d = 1; d < 256; d <<= 1) {
    int x = (t >= d) ? sh[t - d] : 0;
    __syncthreads();
    sh[t] += x;
    __syncthreads();
  }
  if (t < nb) bsum[t] = (t > 0) ? sh[t - 1] : 0;
}

__global__ void fill_csr(const int* __restrict__ dst, const int* __restrict__ offp,
                         const int* __restrict__ bsum, int* __restrict__ tmp,
                         int* __restrict__ eb, int E) {
  int e = blockIdx.x * blockDim.x + threadIdx.x;
  if (e >= E) return;
  int dn = dst[e];
  int pos = offp[dn] + bsum[dn >> 10] + atomicAdd(&tmp[dn], 1);
  eb[pos] = e;
}

// ---------- gather: aggb[node] = sum_e (nf[src]+w0[ef0]+w1[ef1]) + deg*(b0+b1), bf16 out ----------
__global__ void gather_agg(const float* __restrict__ nf,
                           const int* __restrict__ src, const int* __restrict__ ef0,
                           const int* __restrict__ ef1,
                           const float* __restrict__ w0, const float* __restrict__ b0f,
                           const float* __restrict__ w1, const float* __restrict__ b1f,
                           const int* __restrict__ deg, const int* __restrict__ offp,
                           const int* __restrict__ bsum, const int* __restrict__ eb,
                           unsigned short* __restrict__ aggb,
                           int D, int ldab, int total) {
  int idx = blockIdx.x * blockDim.x + threadIdx.x;
  if (idx >= total) return;
  const int quads = ldab >> 2;
  int node = idx / quads;
  int q = idx - node * quads;
  int d = q * 4;
  unsigned short* op = &aggb[(size_t)node * ldab + d];
  if (d >= D) {  // zero the pad columns so GEMM1's A pad is clean
    short4v z = {0, 0, 0, 0};
    *(short4v*)op = z;
    return;
  }
  int dg = deg[node];
  int o = offp[node] + bsum[node >> 10];
  float4v acc = {0.f, 0.f, 0.f, 0.f};
  for (int j = 0; j < dg; ++j) {
    int e = eb[o + j];
    int s = src[e], f0 = ef0[e], f1 = ef1[e];
    float4v nv = *(const float4v*)&nf[(size_t)s * D + d];
    float4v a0 = *(const float4v*)&w0[(size_t)f0 * D + d];
    float4v a1 = *(const float4v*)&w1[(size_t)f1 * D + d];
    acc += nv + a0 + a1;
  }
  float4v bb = *(const float4v*)&b0f[d];
  float4v b2v = *(const float4v*)&b1f[d];
  acc += (float)dg * (bb + b2v);
  short4v r;
#pragma unroll
  for (int j = 0; j < 4; ++j) r[j] = (short)f2b(acc[j]);
  *(short4v*)op = r;
}

// ---------- MFMA GEMM: C = act(A @ B + bias), A bf16 (lda=KP, 16B-aligned rows), ----------
// BT: [n][k] bf16 with ldbt=KP (zero-padded). C fp32 or bf16. Optional column stats.
template<bool RELU, bool STATS, bool CF32>
__global__ __launch_bounds__(256)
void gemm_bias(const short* __restrict__ A, int lda,
               const short* __restrict__ BT, int ldbt,
               const float* __restrict__ bias,
               void* __restrict__ Cv, int ldc,
               int M, int Nn, int KP,
               float* __restrict__ colsum, float* __restrict__ colsumsq) {
  constexpr int BM = 128, BN = 64, BK = 32, SA = 40;  // SA: padded LDS stride (bf16)
  __shared__ __align__(16) short Al[BM * SA];
  __shared__ __align__(16) short Bl[BN * SA];
  const int t = threadIdx.x;
  const int m0 = blockIdx.y * BM;
  const int n0 = blockIdx.x * BN;
  const int wave = t >> 6, lane = t & 63, quad = lane >> 4, lr = lane & 15;
  const int wm = (wave >> 1) * 64, wn = (wave & 1) * 32;

  const float4v fzero = {0.f, 0.f, 0.f, 0.f};
  float4v acc[4][2];
#pragma unroll
  for (int mi = 0; mi < 4; ++mi)
#pragma unroll
    for (int ni = 0; ni < 2; ++ni) acc[mi][ni] = fzero;

  const short8 z8 = {0, 0, 0, 0, 0, 0, 0, 0};

  for (int k0 = 0; k0 < KP; k0 += BK) {
    __syncthreads();
    // ---- stage A tile (BM x BK); A rows padded to lda=KP with zeros ----
#pragma unroll
    for (int l = 0; l < 2; ++l) {
      int g = t + l * 256;            // 0..511
      int row = g >> 2, c = (g & 3) << 3;
      int gm = m0 + row;
      short8 v = z8;
      if (gm < M)
        v = *(const short8*)&A[(size_t)gm * lda + k0 + c];
      *(short8*)&Al[row * SA + c] = v;
    }
    // ---- stage BT tile (BN x BK); rows/cols pre-padded with zeros ----
    {
      int row = t >> 2, c = (t & 3) << 3;
      *(short8*)&Bl[row * SA + c] = *(const short8*)&BT[(size_t)(n0 + row) * ldbt + k0 + c];
    }
    __syncthreads();
    // ---- fragments + MFMA ----
    short8 af[4], bfr[2];
#pragma unroll
    for (int mi = 0; mi < 4; ++mi)
      af[mi] = *(short8*)&Al[(wm + mi * 16 + lr) * SA + quad * 8];
#pragma unroll
    for (int ni = 0; ni < 2; ++ni)
      bfr[ni] = *(short8*)&Bl[(wn + ni * 16 + lr) * SA + quad * 8];
#pragma unroll
    for (int mi = 0; mi < 4; ++mi)
#pragma unroll
      for (int ni = 0; ni < 2; ++ni)
        acc[mi][ni] = __builtin_amdgcn_mfma_f32_16x16x32_bf16(af[mi], bfr[ni], acc[mi][ni], 0, 0, 0);
  }

  // ---- epilogue: bias (+ReLU) (+column stats), store ----
#pragma unroll
  for (int ni = 0; ni < 2; ++ni) {
    int gn = n0 + wn + ni * 16 + lr;
    bool ncol = (gn < Nn);
    float bv = ncol ? bias[gn] : 0.f;
    float s = 0.f, q = 0.f;
#pragma unroll
    for (int mi = 0; mi < 4; ++mi) {
      int gmb = m0 + wm + mi * 16 + quad * 4;
#pragma unroll
      for (int r = 0; r < 4; ++r) {
        int gm = gmb + r;
        float v = acc[mi][ni][r] + bv;
        if (RELU) v = fmaxf(v, 0.f);
        if (gm < M && ncol) {
          if constexpr (CF32) ((float*)Cv)[(size_t)gm * ldc + gn] = v;
          else ((unsigned short*)Cv)[(size_t)gm * ldc + gn] = f2b(v);
          if (STATS) { s += v; q += v * v; }
        }
      }
    }
    if constexpr (STATS) {
      s += __shfl_xor(s, 16); q += __shfl_xor(q, 16);
      s += __shfl_xor(s, 32); q += __shfl_xor(q, 32);
      if (quad == 0 && ncol) {
        unsafeAtomicAdd(&colsum[gn], s);
        unsafeAtomicAdd(&colsumsq[gn], q);
      }
    }
  }
}

// ---------- BatchNorm finalize: scale/shift per column ----------
__global__ void bn_finalize(const float* __restrict__ colsum, const float* __restrict__ colsumsq,
                            const float* __restrict__ gamma, const float* __restrict__ beta,
                            float2* __restrict__ ss, int D, float invN) {
  int d = blockIdx.x * blockDim.x + threadIdx.x;
  if (d >= D) return;
  float mean = colsum[d] * invN;
  float var = fmaxf(colsumsq[d] * invN - mean * mean, 0.f);
  float sc = rsqrtf(var + 1e-5f) * gamma[d];
  float sh = beta[d] - mean * sc;
  ss[d] = make_float2(sc, sh);
}

// ---------- BatchNorm apply (in place on d_out, fp32) ----------
__global__ void bn_apply(float* __restrict__ out, const float2* __restrict__ ss,
                         int total, int D) {
  int idx = blockIdx.x * blockDim.x + threadIdx.x;
  if (idx >= total) return;
  int col = idx % D;
  float2 p = ss[col];
  out[idx] = out[idx] * p.x + p.y;
}

// ---------- launch ----------
extern "C" void kernel_launch(void* const* d_in, const int* in_sizes, int n_in,
                              void* d_out, int out_size, void* d_ws, size_t ws_size,
                              hipStream_t stream) {
  const float* nf  = (const float*)d_in[0];
  const int*   src = (const int*)d_in[1];
  const int*   dst = (const int*)d_in[2];
  const int*   ef0 = (const int*)d_in[3];
  const int*   ef1 = (const int*)d_in[4];
  const float* ew0 = (const float*)d_in[5];
  const float* eb0 = (const float*)d_in[6];
  const float* ew1 = (const float*)d_in[7];
  const float* eb1 = (const float*)d_in[8];
  const float* w1  = (const float*)d_in[9];
  const float* b1  = (const float*)d_in[10];
  const float* w2  = (const float*)d_in[11];
  const float* b2  = (const float*)d_in[12];
  const float* gam = (const float*)d_in[13];
  const float* bet = (const float*)d_in[14];

  const int D = in_sizes[13];        // 300
  const int N = in_sizes[0] / D;     // 100000
  const int E = in_sizes[1];         // 200000
  const int H = in_sizes[10];        // 600
  const int KP1 = (D + 31) / 32 * 32;  // 320
  const int NP1 = (H + 63) / 64 * 64;  // 640
  const int KP2 = (H + 31) / 32 * 32;  // 608
  const int NP2 = (D + 63) / 64 * 64;  // 320
  const int nb  = (N + 1023) / 1024;   // scan blocks (<=256)

  char* ws = (char*)d_ws;
  size_t off = 0;
  // ---- zeroed region ----
  float* colsum   = (float*)(ws + off); off += 4096;
  float* colsumsq = (float*)(ws + off); off += 4096;
  short* wT1      = (short*)(ws + off); off += (size_t)NP1 * KP1 * 2;
  short* wT2      = (short*)(ws + off); off += (size_t)NP2 * KP2 * 2;
  int*   deg      = (int*)(ws + off);   off += (size_t)N * 4;
  int*   tmp      = (int*)(ws + off);   off += (size_t)N * 4;
  size_t zero_bytes = off;
  // ---- uninitialized region ----
  float2* ss      = (float2*)(ws + off); off += 4096;
  int*   offp     = (int*)(ws + off);    off += (size_t)N * 4;
  int*   bsum     = (int*)(ws + off);    off += 4096;
  int*   eb       = (int*)(ws + off);    off += (size_t)E * 4;
  unsigned short* aggb = (unsigned short*)(ws + off); off += (size_t)N * KP1 * 2;
  short* h1       = (short*)(ws + off);  off += (size_t)N * KP2 * 2;

  hipMemsetAsync(d_ws, 0, zero_bytes, stream);

  {  // w1: (D x H) fp32 -> wT1: (H rows x KP1 cols) bf16
    int tot = D * H;
    transpose_pad<<<(tot + 255) / 256, 256, 0, stream>>>(w1, wT1, D, H, KP1, tot);
  }
  {  // w2: (H x D) fp32 -> wT2: (D rows x KP2 cols) bf16
    int tot = H * D;
    transpose_pad<<<(tot + 255) / 256, 256, 0, stream>>>(w2, wT2, H, D, KP2, tot);
  }
  // ---- CSR build ----
  count_deg<<<(E + 255) / 256, 256, 0, stream>>>(dst, deg, E);
  scan1<<<nb, 256, 0, stream>>>(deg, offp, bsum, N);
  scan2<<<1, 256, 0, stream>>>(bsum, nb);
  fill_csr<<<(E + 255) / 256, 256, 0, stream>>>(dst, offp, bsum, tmp, eb, E);
  // ---- gather (atomic-free aggregation, bf16 out) ----
  {
    int total = N * (KP1 / 4);
    gather_agg<<<(total + 255) / 256, 256, 0, stream>>>(
        nf, src, ef0, ef1, ew0, eb0, ew1, eb1, deg, offp, bsum, eb,
        aggb, D, KP1, total);
  }
  {  // h1 = relu(aggb @ w1 + b1), bf16 out (stride KP2)
    dim3 grid(NP1 / 64, (N + 127) / 128);
    gemm_bias<true, false, false><<<grid, 256, 0, stream>>>(
        (const short*)aggb, KP1, wT1, KP1, b1, h1, KP2, N, H, KP1, nullptr, nullptr);
  }
  {  // h = h1 @ w2 + b2 (+ column stats), fp32 out
    dim3 grid(NP2 / 64, (N + 127) / 128);
    gemm_bias<false, true, true><<<grid, 256, 0, stream>>>(
        h1, KP2, wT2, KP2, b2, d_out, D, N, D, KP2, colsum, colsumsq);
  }
  bn_finalize<<<(D + 255) / 256, 256, 0, stream>>>(colsum, colsumsq, gam, bet, ss, D,
                                                   1.0f / (float)N);
  {
    int tot = N * D;
    bn_apply<<<(tot + 255) / 256, 256, 0, stream>>>((float*)d_out, ss, tot, D);
  }
}